// Round 6
// baseline (1327.057 us; speedup 1.0000x reference)
//
#include <hip/hip_runtime.h>
#include <hip/hip_bf16.h>

typedef short bf16x8 __attribute__((ext_vector_type(8)));
typedef float f32x4 __attribute__((ext_vector_type(4)));
typedef unsigned short u16x8 __attribute__((ext_vector_type(8)));

#define DEVI static __device__ __forceinline__

constexpr int Bb = 4, Hh = 16, Ss = 2048, Dd = 64;
constexpr int BH = Bb * Hh;
constexpr float SCALE = 0.125f;                    // 1/sqrt(64)
constexpr long QKV_ELEMS = (long)BH * Ss * Dd;     // 8,388,608
constexpr long MASK_ELEMS = (long)BH * Ss * Ss;    // 268,435,456

DEVI unsigned short f2bf(float f) {
  __hip_bfloat16 h = __float2bfloat16(f);
  unsigned short u;
  __builtin_memcpy(&u, &h, 2);
  return u;
}
DEVI float bflo(unsigned int u) { unsigned int x = u << 16;        float f; __builtin_memcpy(&f, &x, 4); return f; }
DEVI float bfhi(unsigned int u) { unsigned int x = u & 0xffff0000u; float f; __builtin_memcpy(&f, &x, 4); return f; }

// swizzled byte offset into 8-row P tile: row r (4096B each), XOR spreads banks
DEVI int p8(int r, int k) { return (r << 12) + ((k << 1) ^ (r << 4)); }

DEVI bf16x8 cvt8(const float* p) {
  float4 a = *reinterpret_cast<const float4*>(p);
  float4 b = *reinterpret_cast<const float4*>(p + 4);
  bf16x8 r;
  r[0] = (short)f2bf(a.x); r[1] = (short)f2bf(a.y); r[2] = (short)f2bf(a.z); r[3] = (short)f2bf(a.w);
  r[4] = (short)f2bf(b.x); r[5] = (short)f2bf(b.y); r[6] = (short)f2bf(b.z); r[7] = (short)f2bf(b.w);
  return r;
}

// ---------------- prologue: mask int32 -> 1 bit/elem ----------------
__global__ __launch_bounds__(256) void bitpack(const int* __restrict__ mask,
                                               unsigned long long* __restrict__ bits)
{
  const long wid = (((long)blockIdx.x * 256 + threadIdx.x) >> 6);
  const int lane = threadIdx.x & 63;
  const long NW = ((long)gridDim.x * 256) >> 6;
  for (long W = wid; W < (MASK_ELEMS >> 8); W += NW) {
    const int* p = mask + (W << 8) + lane;
    const unsigned long long b0 = __ballot(__builtin_nontemporal_load(p) != 0);
    const unsigned long long b1 = __ballot(__builtin_nontemporal_load(p + 64) != 0);
    const unsigned long long b2 = __ballot(__builtin_nontemporal_load(p + 128) != 0);
    const unsigned long long b3 = __ballot(__builtin_nontemporal_load(p + 192) != 0);
    if (lane == 0) {
      ulonglong4 o; o.x = b0; o.y = b1; o.z = b2; o.w = b3;
      *reinterpret_cast<ulonglong4*>(bits + (W << 2)) = o;
    }
  }
}

// ---------------- prologue: fp32 -> bf16 casts ----------------
__global__ __launch_bounds__(256) void cvt_qk(const float* __restrict__ q, const float* __restrict__ k,
                                              unsigned short* __restrict__ qb, unsigned short* __restrict__ kb)
{
  const long i = ((long)blockIdx.x * 256 + threadIdx.x) * 4;
  if (i >= QKV_ELEMS) return;
  const float4 a = *reinterpret_cast<const float4*>(q + i);
  ushort4 oa; oa.x = f2bf(a.x); oa.y = f2bf(a.y); oa.z = f2bf(a.z); oa.w = f2bf(a.w);
  *reinterpret_cast<ushort4*>(qb + i) = oa;
  const float4 b = *reinterpret_cast<const float4*>(k + i);
  ushort4 ob; ob.x = f2bf(b.x); ob.y = f2bf(b.y); ob.z = f2bf(b.z); ob.w = f2bf(b.w);
  *reinterpret_cast<ushort4*>(kb + i) = ob;
}

// V [bh][s][d] fp32 -> Vt [bh][d][s] bf16
__global__ __launch_bounds__(256) void cvt_vt(const float* __restrict__ v, unsigned short* __restrict__ vt)
{
  __shared__ float tile[64][65];
  const int bh = blockIdx.x >> 5;
  const int s0 = (blockIdx.x & 31) << 6;
  const int t  = threadIdx.x;
  {
    const int c = (t & 15) << 2;
    const float* src = v + ((long)bh * Ss + s0) * Dd;
    for (int rr = (t >> 4); rr < 64; rr += 16) {
      const float4 a = *reinterpret_cast<const float4*>(src + rr * Dd + c);
      tile[rr][c] = a.x; tile[rr][c + 1] = a.y; tile[rr][c + 2] = a.z; tile[rr][c + 3] = a.w;
    }
  }
  __syncthreads();
  {
    const int d  = t >> 2;
    const int sc = (t & 3) << 4;
    unsigned short* dst = vt + ((long)bh * Dd + d) * Ss + s0 + sc;
    u16x8 v0, v1;
#pragma unroll
    for (int j = 0; j < 8; ++j) v0[j] = f2bf(tile[sc + j][d]);
#pragma unroll
    for (int j = 0; j < 8; ++j) v1[j] = f2bf(tile[sc + 8 + j][d]);
    *reinterpret_cast<u16x8*>(dst)     = v0;
    *reinterpret_cast<u16x8*>(dst + 8) = v1;
  }
}

// ---------------- main fused attention (one-pass, 8 q-rows/block) ----------------
// Block = 8 q-rows of one (b,h), 4 waves, wave w owns keys [512w, 512w+512) in phase 1.
// P (unnormalized exp, bf16) in 32KB swizzled LDS; Ored[8][64] aliases P after PV.
// Phase 3: wave w owns d-cols [16w,16w+16) over ALL keys -> no cross-wave sum.
template<bool PRE>
__global__ __launch_bounds__(256, 4)
void attn_main(const float* __restrict__ qf, const float* __restrict__ kf,
               const float* __restrict__ vf, const int* __restrict__ mask,
               const unsigned short* __restrict__ qb,
               const unsigned short* __restrict__ kbp,
               const unsigned short* __restrict__ vt,
               const unsigned* __restrict__ bits32,
               float* __restrict__ out, float* __restrict__ attn)
{
  __shared__ __align__(16) unsigned char Pb[8 * 4096];  // P rows; later aliased as Ored[8][64] f32
  __shared__ float rpart[4][8];
  __shared__ float rinv8[8];

  const int tid  = threadIdx.x;
  const int wave = tid >> 6;
  const int lane = tid & 63;
  const int l15  = lane & 15;
  const int lg   = lane >> 4;
  const int r8   = l15 & 7;

  const int bh    = blockIdx.x >> 8;          // 256 blocks per (b,h)
  const int qbase = (blockIdx.x & 255) << 3;  // 8 rows
  const int wbase = wave << 9;

  // Q fragment (B operand of swapped QK^T): col q = l15 (cols >=8 duplicate r8)
  bf16x8 qfr0, qfr1;
  {
    const long qrow = (long)(bh * Ss + qbase + r8) * Dd + lg * 8;
    if (PRE) {
      qfr0 = *reinterpret_cast<const bf16x8*>(qb + qrow);
      qfr1 = *reinterpret_cast<const bf16x8*>(qb + qrow + 32);
    } else {
      qfr0 = cvt8(qf + qrow);
      qfr1 = cvt8(qf + qrow + 32);
    }
  }

  const long mrowQ = (long)(bh * Ss + qbase + r8) * Ss;
  float psum = 0.f;

  // ---- Phase 1: QK^T, masked exp (unnormalized), P->LDS, rowsum ----
  for (int it = 0; it < 16; ++it) {
    const int key0 = wbase + (it << 5);
    const long kr0 = (long)(bh * Ss + key0 + l15) * Dd + lg * 8;
    bf16x8 kA0, kA1, kB0, kB1;
    if (PRE) {
      kA0 = *reinterpret_cast<const bf16x8*>(kbp + kr0);
      kA1 = *reinterpret_cast<const bf16x8*>(kbp + kr0 + 32);
      kB0 = *reinterpret_cast<const bf16x8*>(kbp + kr0 + 16 * Dd);
      kB1 = *reinterpret_cast<const bf16x8*>(kbp + kr0 + 16 * Dd + 32);
    } else {
      kA0 = cvt8(kf + kr0);           kA1 = cvt8(kf + kr0 + 32);
      kB0 = cvt8(kf + kr0 + 16 * Dd); kB1 = cvt8(kf + kr0 + 16 * Dd + 32);
    }
    unsigned mm;
    if (PRE) {
      const unsigned w32 = bits32[(unsigned long long)(mrowQ + key0) >> 5];
      mm = ((w32 >> (lg * 4)) & 0xFu) | (((w32 >> (16 + lg * 4)) & 0xFu) << 4);
    } else {
      const int4 m0 = *reinterpret_cast<const int4*>(mask + mrowQ + key0 + lg * 4);
      const int4 m1 = *reinterpret_cast<const int4*>(mask + mrowQ + key0 + 16 + lg * 4);
      mm = (m0.x ? 1u : 0u) | (m0.y ? 2u : 0u) | (m0.z ? 4u : 0u) | (m0.w ? 8u : 0u)
         | (m1.x ? 16u : 0u) | (m1.y ? 32u : 0u) | (m1.z ? 64u : 0u) | (m1.w ? 128u : 0u);
    }
    f32x4 aA = {0.f, 0.f, 0.f, 0.f}, aB = {0.f, 0.f, 0.f, 0.f};
    aA = __builtin_amdgcn_mfma_f32_16x16x32_bf16(kA0, qfr0, aA, 0, 0, 0);
    aA = __builtin_amdgcn_mfma_f32_16x16x32_bf16(kA1, qfr1, aA, 0, 0, 0);
    aB = __builtin_amdgcn_mfma_f32_16x16x32_bf16(kB0, qfr0, aB, 0, 0, 0);
    aB = __builtin_amdgcn_mfma_f32_16x16x32_bf16(kB1, qfr1, aB, 0, 0, 0);
    const float p0 = (mm &   1u) ? __expf(aA[0] * SCALE) : 0.f;
    const float p1 = (mm &   2u) ? __expf(aA[1] * SCALE) : 0.f;
    const float p2 = (mm &   4u) ? __expf(aA[2] * SCALE) : 0.f;
    const float p3 = (mm &   8u) ? __expf(aA[3] * SCALE) : 0.f;
    const float p4 = (mm &  16u) ? __expf(aB[0] * SCALE) : 0.f;
    const float p5 = (mm &  32u) ? __expf(aB[1] * SCALE) : 0.f;
    const float p6 = (mm &  64u) ? __expf(aB[2] * SCALE) : 0.f;
    const float p7 = (mm & 128u) ? __expf(aB[3] * SCALE) : 0.f;
    psum += ((p0 + p1) + (p2 + p3)) + ((p4 + p5) + (p6 + p7));
    uint2 w0, w1;
    w0.x = (unsigned)f2bf(p0) | ((unsigned)f2bf(p1) << 16);
    w0.y = (unsigned)f2bf(p2) | ((unsigned)f2bf(p3) << 16);
    w1.x = (unsigned)f2bf(p4) | ((unsigned)f2bf(p5) << 16);
    w1.y = (unsigned)f2bf(p6) | ((unsigned)f2bf(p7) << 16);
    // lanes l15<8 write the low 16 keys, duplicates (l15>=8) write the high 16
    const int  addr = (l15 < 8) ? p8(r8, key0 + lg * 4) : p8(r8, key0 + 16 + lg * 4);
    const uint2 wv  = (l15 < 8) ? w0 : w1;
    *reinterpret_cast<uint2*>(Pb + addr) = wv;
  }

  psum += __shfl_xor(psum, 16);
  psum += __shfl_xor(psum, 32);
  if (lane < 8) rpart[wave][lane] = psum;
  __syncthreads();
  if (tid < 8) {
    const float t = rpart[0][tid] + rpart[1][tid] + rpart[2][tid] + rpart[3][tid];
    rinv8[tid] = (t > 0.f) ? (1.f / t) : 0.f;
  }
  __syncthreads();

  // ---- Phase 2: normalize + write attn (plain coalesced f32x4) ----
  {
    const int r  = (wave << 1) + (lane >> 5);
    const int cb = (lane & 31) << 3;
    const float inv = rinv8[r];
    float* arow = attn + (long)(bh * Ss + qbase + r) * Ss;
#pragma unroll
    for (int ch = 0; ch < 8; ++ch) {
      const int c0 = cb + (ch << 8);
      const uint4 pk = *reinterpret_cast<const uint4*>(Pb + p8(r, c0));
      f32x4 o0, o1;
      o0[0] = bflo(pk.x) * inv; o0[1] = bfhi(pk.x) * inv;
      o0[2] = bflo(pk.y) * inv; o0[3] = bfhi(pk.y) * inv;
      o1[0] = bflo(pk.z) * inv; o1[1] = bfhi(pk.z) * inv;
      o1[2] = bflo(pk.w) * inv; o1[3] = bfhi(pk.w) * inv;
      *reinterpret_cast<f32x4*>(arow + c0)     = o0;
      *reinterpret_cast<f32x4*>(arow + c0 + 4) = o1;
    }
  }

  // ---- Phase 3: O = P·V via MFMA; wave w owns d-cols [16w,16w+16) over ALL keys ----
  f32x4 oacc = {0.f, 0.f, 0.f, 0.f};
  const int dcol = (wave << 4) + l15;
  {
    const unsigned short* vrow = PRE ? (vt + (long)(bh * Dd + dcol) * Ss) : nullptr;
    const float* vcolf = PRE ? nullptr : (vf + (long)bh * Ss * Dd + dcol);
    for (int kk = 0; kk < Ss; kk += 32) {
      const int ka = kk + (lg << 3);
      const bf16x8 af = *reinterpret_cast<const bf16x8*>(Pb + p8(r8, ka));
      bf16x8 bfr;
      if (PRE) {
        bfr = *reinterpret_cast<const bf16x8*>(vrow + ka);
      } else {
#pragma unroll
        for (int e = 0; e < 8; ++e) bfr[e] = (short)f2bf(vcolf[(long)(ka + e) * Dd]);
      }
      oacc = __builtin_amdgcn_mfma_f32_16x16x32_bf16(af, bfr, oacc, 0, 0, 0);
    }
  }
  __syncthreads();                       // all P reads done; alias Pb as Ored[8][64]
  float* OredF = reinterpret_cast<float*>(Pb);
  if (lg < 2) {                          // rows 0..7 only (rows 8..15 are duplicates)
#pragma unroll
    for (int r = 0; r < 4; ++r)
      OredF[((lg << 2) + r) * 64 + dcol] = oacc[r];
  }
  __syncthreads();
  if (tid < 128) {
    f32x4 t = reinterpret_cast<const f32x4*>(Pb)[tid];
    t *= rinv8[tid >> 4];
    *reinterpret_cast<f32x4*>(out + (long)(bh * Ss + qbase) * Dd + (tid << 2)) = t;
  }
}

extern "C" void kernel_launch(void* const* d_in, const int* in_sizes, int n_in,
                              void* d_out, int out_size, void* d_ws, size_t ws_size,
                              hipStream_t stream)
{
  const float* q    = (const float*)d_in[0];
  const float* k    = (const float*)d_in[1];
  const float* v    = (const float*)d_in[2];
  const int*   mask = (const int*)d_in[3];
  float* out  = (float*)d_out;
  float* attn = out + QKV_ELEMS;

  const size_t bf16_bytes = (size_t)QKV_ELEMS * 2 * 3;          // qb + kb + vt
  const size_t bits_bytes = (size_t)(MASK_ELEMS >> 3);          // 32 MiB
  const size_t need = bf16_bytes + bits_bytes;
  if (ws_size >= need) {
    unsigned short* qb = (unsigned short*)d_ws;
    unsigned short* kb = qb + QKV_ELEMS;
    unsigned short* vt = kb + QKV_ELEMS;
    unsigned long long* bits = (unsigned long long*)((char*)d_ws + bf16_bytes);
    hipLaunchKernelGGL(bitpack, dim3(2048), dim3(256), 0, stream, mask, bits);
    hipLaunchKernelGGL(cvt_qk, dim3((unsigned)(QKV_ELEMS / 1024)), dim3(256), 0, stream, q, k, qb, kb);
    hipLaunchKernelGGL(cvt_vt, dim3(BH * 32), dim3(256), 0, stream, v, vt);
    hipLaunchKernelGGL((attn_main<true>), dim3(BH * 256), dim3(256), 0, stream,
                       q, k, v, mask, qb, kb, vt, (const unsigned*)bits, out, attn);
  } else {
    hipLaunchKernelGGL((attn_main<false>), dim3(BH * 256), dim3(256), 0, stream,
                       q, k, v, mask, nullptr, nullptr, nullptr, nullptr, out, attn);
  }
}

// Round 7
// 945.515 us; speedup vs baseline: 1.4035x; 1.4035x over previous
//
#include <hip/hip_runtime.h>
#include <hip/hip_bf16.h>

typedef short bf16x8 __attribute__((ext_vector_type(8)));
typedef float f32x4 __attribute__((ext_vector_type(4)));
typedef unsigned short u16x8 __attribute__((ext_vector_type(8)));

#define DEVI static __device__ __forceinline__

constexpr int Bb = 4, Hh = 16, Ss = 2048, Dd = 64;
constexpr int BH = Bb * Hh;
constexpr float SCALE = 0.125f;                    // 1/sqrt(64)
constexpr long QKV_ELEMS = (long)BH * Ss * Dd;     // 8,388,608
constexpr long MASK_ELEMS = (long)BH * Ss * Ss;    // 268,435,456

DEVI unsigned short f2bf(float f) {
  __hip_bfloat16 h = __float2bfloat16(f);
  unsigned short u;
  __builtin_memcpy(&u, &h, 2);
  return u;
}
DEVI float bflo(unsigned int u) { unsigned int x = u << 16;        float f; __builtin_memcpy(&f, &x, 4); return f; }
DEVI float bfhi(unsigned int u) { unsigned int x = u & 0xffff0000u; float f; __builtin_memcpy(&f, &x, 4); return f; }

// swizzled byte offset into the P LDS tile: row q (16 rows x 4096B), XOR spreads banks
DEVI int pidx(int q, int k) { return (q << 12) + ((k << 1) ^ ((q & 7) << 4)); }

DEVI bf16x8 cvt8(const float* p) {
  float4 a = *reinterpret_cast<const float4*>(p);
  float4 b = *reinterpret_cast<const float4*>(p + 4);
  bf16x8 r;
  r[0] = (short)f2bf(a.x); r[1] = (short)f2bf(a.y); r[2] = (short)f2bf(a.z); r[3] = (short)f2bf(a.w);
  r[4] = (short)f2bf(b.x); r[5] = (short)f2bf(b.y); r[6] = (short)f2bf(b.z); r[7] = (short)f2bf(b.w);
  return r;
}

// ---------------- prologue: mask int32 -> 1 bit/elem ----------------
__global__ __launch_bounds__(256) void bitpack(const int* __restrict__ mask,
                                               unsigned long long* __restrict__ bits)
{
  const long wid = (((long)blockIdx.x * 256 + threadIdx.x) >> 6);
  const int lane = threadIdx.x & 63;
  const long NW = ((long)gridDim.x * 256) >> 6;
  for (long W = wid; W < (MASK_ELEMS >> 8); W += NW) {
    const int* p = mask + (W << 8) + lane;
    const unsigned long long b0 = __ballot(__builtin_nontemporal_load(p) != 0);
    const unsigned long long b1 = __ballot(__builtin_nontemporal_load(p + 64) != 0);
    const unsigned long long b2 = __ballot(__builtin_nontemporal_load(p + 128) != 0);
    const unsigned long long b3 = __ballot(__builtin_nontemporal_load(p + 192) != 0);
    if (lane == 0) {
      ulonglong4 o; o.x = b0; o.y = b1; o.z = b2; o.w = b3;
      *reinterpret_cast<ulonglong4*>(bits + (W << 2)) = o;
    }
  }
}

// ---------------- prologue: fp32 -> bf16 casts ----------------
__global__ __launch_bounds__(256) void cvt_qk(const float* __restrict__ q, const float* __restrict__ k,
                                              unsigned short* __restrict__ qb, unsigned short* __restrict__ kb)
{
  const long i = ((long)blockIdx.x * 256 + threadIdx.x) * 4;
  if (i >= QKV_ELEMS) return;
  const float4 a = *reinterpret_cast<const float4*>(q + i);
  ushort4 oa; oa.x = f2bf(a.x); oa.y = f2bf(a.y); oa.z = f2bf(a.z); oa.w = f2bf(a.w);
  *reinterpret_cast<ushort4*>(qb + i) = oa;
  const float4 b = *reinterpret_cast<const float4*>(k + i);
  ushort4 ob; ob.x = f2bf(b.x); ob.y = f2bf(b.y); ob.z = f2bf(b.z); ob.w = f2bf(b.w);
  *reinterpret_cast<ushort4*>(kb + i) = ob;
}

// V [bh][s][d] fp32 -> Vt [bh][d][s] bf16
__global__ __launch_bounds__(256) void cvt_vt(const float* __restrict__ v, unsigned short* __restrict__ vt)
{
  __shared__ float tile[64][65];
  const int bh = blockIdx.x >> 5;
  const int s0 = (blockIdx.x & 31) << 6;
  const int t  = threadIdx.x;
  {
    const int c = (t & 15) << 2;
    const float* src = v + ((long)bh * Ss + s0) * Dd;
    for (int rr = (t >> 4); rr < 64; rr += 16) {
      const float4 a = *reinterpret_cast<const float4*>(src + rr * Dd + c);
      tile[rr][c] = a.x; tile[rr][c + 1] = a.y; tile[rr][c + 2] = a.z; tile[rr][c + 3] = a.w;
    }
  }
  __syncthreads();
  {
    const int d  = t >> 2;
    const int sc = (t & 3) << 4;
    unsigned short* dst = vt + ((long)bh * Dd + d) * Ss + s0 + sc;
    u16x8 v0, v1;
#pragma unroll
    for (int j = 0; j < 8; ++j) v0[j] = f2bf(tile[sc + j][d]);
#pragma unroll
    for (int j = 0; j < 8; ++j) v1[j] = f2bf(tile[sc + 8 + j][d]);
    *reinterpret_cast<u16x8*>(dst)     = v0;
    *reinterpret_cast<u16x8*>(dst + 8) = v1;
  }
}

// ---------------- main fused attention ----------------
// 1 block = 16 q-rows of one (b,h); 4 waves; P (exp scores) in swizzled bf16 LDS.
template<bool PRE>
__global__ __launch_bounds__(256, 2)
void attn_main(const float* __restrict__ qf, const float* __restrict__ kf,
               const float* __restrict__ vf, const int* __restrict__ mask,
               const unsigned short* __restrict__ qb,
               const unsigned short* __restrict__ kbp,
               const unsigned short* __restrict__ vt,
               const unsigned long long* __restrict__ bits,
               float* __restrict__ out, float* __restrict__ attn)
{
  __shared__ __align__(16) char Pb[16 * 2048 * 2];
  __shared__ float rpart[4][16];
  __shared__ float rinv[16];

  const int tid  = threadIdx.x;
  const int wave = tid >> 6;
  const int lane = tid & 63;
  const int l15  = lane & 15;
  const int lg   = lane >> 4;

  const int bh    = blockIdx.x >> 7;
  const int qbase = (blockIdx.x & 127) << 4;

  // Q fragments (B operand of swapped QK^T): n = q = lane&15, k-dim = d
  bf16x8 qfrag0, qfrag1;
  {
    const long qrow = (long)(bh * Ss + qbase + l15) * Dd + lg * 8;
    if (PRE) {
      qfrag0 = *reinterpret_cast<const bf16x8*>(qb + qrow);
      qfrag1 = *reinterpret_cast<const bf16x8*>(qb + qrow + 32);
    } else {
      qfrag0 = cvt8(qf + qrow);
      qfrag1 = cvt8(qf + qrow + 32);
    }
  }

  float psum = 0.f;
  const long mrow = (long)(bh * Ss + qbase + l15) * Ss;   // this lane's q-row (element index)

  // Phase 1: S^T = K·Q^T per 16-key tile; exp+mask; scatter into LDS; rowsum
  for (int kt = 0; kt < Ss; kt += 64) {
    const int key0 = kt + (wave << 4);
    bf16x8 kfrag0, kfrag1;
    const long krow = (long)(bh * Ss + key0 + l15) * Dd + lg * 8;
    if (PRE) {
      kfrag0 = *reinterpret_cast<const bf16x8*>(kbp + krow);
      kfrag1 = *reinterpret_cast<const bf16x8*>(kbp + krow + 32);
    } else {
      kfrag0 = cvt8(kf + krow);
      kfrag1 = cvt8(kf + krow + 32);
    }
    const int k0 = key0 + (lg << 2);                      // 4 consecutive keys per lane
    unsigned mm;
    if (PRE) {
      const unsigned long long e = (unsigned long long)(mrow + k0);
      const unsigned long long w = bits[e >> 6];
      mm = (unsigned)(w >> ((int)e & 63)) & 0xFu;
    } else {
      const int4 m4 = *reinterpret_cast<const int4*>(mask + mrow + k0);
      mm = (m4.x ? 1u : 0u) | (m4.y ? 2u : 0u) | (m4.z ? 4u : 0u) | (m4.w ? 8u : 0u);
    }
    f32x4 acc = {0.f, 0.f, 0.f, 0.f};
    acc = __builtin_amdgcn_mfma_f32_16x16x32_bf16(kfrag0, qfrag0, acc, 0, 0, 0);
    acc = __builtin_amdgcn_mfma_f32_16x16x32_bf16(kfrag1, qfrag1, acc, 0, 0, 0);
    const float p0 = (mm & 1u) ? __expf(acc[0] * SCALE) : 0.f;
    const float p1 = (mm & 2u) ? __expf(acc[1] * SCALE) : 0.f;
    const float p2 = (mm & 4u) ? __expf(acc[2] * SCALE) : 0.f;
    const float p3 = (mm & 8u) ? __expf(acc[3] * SCALE) : 0.f;
    psum += (p0 + p1) + (p2 + p3);
    uint2 w2;
    w2.x = (unsigned)f2bf(p0) | ((unsigned)f2bf(p1) << 16);
    w2.y = (unsigned)f2bf(p2) | ((unsigned)f2bf(p3) << 16);
    *reinterpret_cast<uint2*>(Pb + pidx(l15, k0)) = w2;
  }

  // row-sum reduce: lanes with equal l15 share a q-row
  psum += __shfl_xor(psum, 16);
  psum += __shfl_xor(psum, 32);
  if (lane < 16) rpart[wave][l15] = psum;
  __syncthreads();
  if (tid < 16) {
    const float t = rpart[0][tid] + rpart[1][tid] + rpart[2][tid] + rpart[3][tid];
    rinv[tid] = (t > 0.f) ? (1.f / t) : 0.f;
  }
  __syncthreads();

  // Phase 2: normalize + write attn (fp32, coalesced 16B, nontemporal full-line)
  {
    const int r  = tid >> 4;
    const int cs = (tid & 15) << 3;
    const float inv = rinv[r];
    float* arow = attn + (long)(bh * Ss + qbase + r) * Ss;
#pragma unroll
    for (int it = 0; it < 16; ++it) {
      const int c0 = cs + (it << 7);
      const uint4 pk = *reinterpret_cast<const uint4*>(Pb + pidx(r, c0));
      f32x4 o0, o1;
      o0[0] = bflo(pk.x) * inv; o0[1] = bfhi(pk.x) * inv;
      o0[2] = bflo(pk.y) * inv; o0[3] = bfhi(pk.y) * inv;
      o1[0] = bflo(pk.z) * inv; o1[1] = bfhi(pk.z) * inv;
      o1[2] = bflo(pk.w) * inv; o1[3] = bfhi(pk.w) * inv;
      __builtin_nontemporal_store(o0, reinterpret_cast<f32x4*>(arow + c0));
      __builtin_nontemporal_store(o1, reinterpret_cast<f32x4*>(arow + c0 + 4));
    }
  }

  // Phase 3: O = P·V via MFMA; wave w owns d-columns [16w, 16w+16)
  {
    const int dcol = (wave << 4) + l15;
    f32x4 oacc = {0.f, 0.f, 0.f, 0.f};
    const unsigned short* vrow = PRE ? (vt + (long)(bh * Dd + dcol) * Ss) : nullptr;
    const float* vcolf = PRE ? nullptr : (vf + (long)bh * Ss * Dd + dcol);
    for (int kk = 0; kk < Ss; kk += 32) {
      const int ka = kk + (lg << 3);
      const bf16x8 afrag = *reinterpret_cast<const bf16x8*>(Pb + pidx(l15, ka));
      bf16x8 bfrag;
      if (PRE) {
        bfrag = *reinterpret_cast<const bf16x8*>(vrow + ka);
      } else {
#pragma unroll
        for (int e = 0; e < 8; ++e) bfrag[e] = (short)f2bf(vcolf[(long)(ka + e) * Dd]);
      }
      oacc = __builtin_amdgcn_mfma_f32_16x16x32_bf16(afrag, bfrag, oacc, 0, 0, 0);
    }
    float* obase = out + (long)(bh * Ss + qbase) * Dd + dcol;
#pragma unroll
    for (int rg = 0; rg < 4; ++rg) {
      const int qrow = (lg << 2) + rg;
      obase[qrow * Dd] = oacc[rg] * rinv[qrow];   // plain store: L2 write-combines
    }
  }
}

extern "C" void kernel_launch(void* const* d_in, const int* in_sizes, int n_in,
                              void* d_out, int out_size, void* d_ws, size_t ws_size,
                              hipStream_t stream)
{
  const float* q    = (const float*)d_in[0];
  const float* k    = (const float*)d_in[1];
  const float* v    = (const float*)d_in[2];
  const int*   mask = (const int*)d_in[3];
  float* out  = (float*)d_out;
  float* attn = out + QKV_ELEMS;

  const size_t bf16_bytes = (size_t)QKV_ELEMS * 2 * 3;          // qb + kb + vt
  const size_t bits_bytes = (size_t)(MASK_ELEMS >> 3);          // 32 MiB
  const size_t need = bf16_bytes + bits_bytes;
  if (ws_size >= need) {
    unsigned short* qb = (unsigned short*)d_ws;
    unsigned short* kb = qb + QKV_ELEMS;
    unsigned short* vt = kb + QKV_ELEMS;
    unsigned long long* bits = (unsigned long long*)((char*)d_ws + bf16_bytes);
    hipLaunchKernelGGL(bitpack, dim3(2048), dim3(256), 0, stream, mask, bits);
    hipLaunchKernelGGL(cvt_qk, dim3((unsigned)(QKV_ELEMS / 1024)), dim3(256), 0, stream, q, k, qb, kb);
    hipLaunchKernelGGL(cvt_vt, dim3(BH * 32), dim3(256), 0, stream, v, vt);
    hipLaunchKernelGGL((attn_main<true>), dim3(BH * 128), dim3(256), 0, stream,
                       q, k, v, mask, qb, kb, vt, bits, out, attn);
  } else {
    hipLaunchKernelGGL((attn_main<false>), dim3(BH * 128), dim3(256), 0, stream,
                       q, k, v, mask, nullptr, nullptr, nullptr, nullptr, out, attn);
  }
}

// Round 8
// 915.230 us; speedup vs baseline: 1.4500x; 1.0331x over previous
//
#include <hip/hip_runtime.h>
#include <hip/hip_bf16.h>

typedef short bf16x8 __attribute__((ext_vector_type(8)));
typedef float f32x4 __attribute__((ext_vector_type(4)));
typedef unsigned short u16x8 __attribute__((ext_vector_type(8)));

#define DEVI static __device__ __forceinline__

constexpr int Bb = 4, Hh = 16, Ss = 2048, Dd = 64;
constexpr int BH = Bb * Hh;
constexpr float SCALE = 0.125f;                    // 1/sqrt(64)
constexpr long QKV_ELEMS = (long)BH * Ss * Dd;     // 8,388,608
constexpr long MASK_ELEMS = (long)BH * Ss * Ss;    // 268,435,456

DEVI unsigned short f2bf(float f) {
  __hip_bfloat16 h = __float2bfloat16(f);
  unsigned short u;
  __builtin_memcpy(&u, &h, 2);
  return u;
}
DEVI float bflo(unsigned int u) { unsigned int x = u << 16;        float f; __builtin_memcpy(&f, &x, 4); return f; }
DEVI float bfhi(unsigned int u) { unsigned int x = u & 0xffff0000u; float f; __builtin_memcpy(&f, &x, 4); return f; }

// swizzled byte offset into the P LDS tile: row q (16 rows x 4096B), XOR spreads banks
DEVI int pidx(int q, int k) { return (q << 12) + ((k << 1) ^ ((q & 7) << 4)); }

DEVI bf16x8 cvt8(const float* p) {
  float4 a = *reinterpret_cast<const float4*>(p);
  float4 b = *reinterpret_cast<const float4*>(p + 4);
  bf16x8 r;
  r[0] = (short)f2bf(a.x); r[1] = (short)f2bf(a.y); r[2] = (short)f2bf(a.z); r[3] = (short)f2bf(a.w);
  r[4] = (short)f2bf(b.x); r[5] = (short)f2bf(b.y); r[6] = (short)f2bf(b.z); r[7] = (short)f2bf(b.w);
  return r;
}

// ---------------- prologue: mask int32 -> 1 bit/elem ----------------
__global__ __launch_bounds__(256) void bitpack(const int* __restrict__ mask,
                                               unsigned long long* __restrict__ bits)
{
  const long wid = (((long)blockIdx.x * 256 + threadIdx.x) >> 6);
  const int lane = threadIdx.x & 63;
  const long NW = ((long)gridDim.x * 256) >> 6;
  for (long W = wid; W < (MASK_ELEMS >> 8); W += NW) {
    const int* p = mask + (W << 8) + lane;
    const unsigned long long b0 = __ballot(__builtin_nontemporal_load(p) != 0);
    const unsigned long long b1 = __ballot(__builtin_nontemporal_load(p + 64) != 0);
    const unsigned long long b2 = __ballot(__builtin_nontemporal_load(p + 128) != 0);
    const unsigned long long b3 = __ballot(__builtin_nontemporal_load(p + 192) != 0);
    if (lane == 0) {
      ulonglong4 o; o.x = b0; o.y = b1; o.z = b2; o.w = b3;
      *reinterpret_cast<ulonglong4*>(bits + (W << 2)) = o;
    }
  }
}

// ---------------- prologue: fp32 -> bf16 casts ----------------
__global__ __launch_bounds__(256) void cvt_qk(const float* __restrict__ q, const float* __restrict__ k,
                                              unsigned short* __restrict__ qb, unsigned short* __restrict__ kb)
{
  const long i = ((long)blockIdx.x * 256 + threadIdx.x) * 4;
  if (i >= QKV_ELEMS) return;
  const float4 a = *reinterpret_cast<const float4*>(q + i);
  ushort4 oa; oa.x = f2bf(a.x); oa.y = f2bf(a.y); oa.z = f2bf(a.z); oa.w = f2bf(a.w);
  *reinterpret_cast<ushort4*>(qb + i) = oa;
  const float4 b = *reinterpret_cast<const float4*>(k + i);
  ushort4 ob; ob.x = f2bf(b.x); ob.y = f2bf(b.y); ob.z = f2bf(b.z); ob.w = f2bf(b.w);
  *reinterpret_cast<ushort4*>(kb + i) = ob;
}

// V [bh][s][d] fp32 -> Vt [bh][d][s] bf16
__global__ __launch_bounds__(256) void cvt_vt(const float* __restrict__ v, unsigned short* __restrict__ vt)
{
  __shared__ float tile[64][65];
  const int bh = blockIdx.x >> 5;
  const int s0 = (blockIdx.x & 31) << 6;
  const int t  = threadIdx.x;
  {
    const int c = (t & 15) << 2;
    const float* src = v + ((long)bh * Ss + s0) * Dd;
    for (int rr = (t >> 4); rr < 64; rr += 16) {
      const float4 a = *reinterpret_cast<const float4*>(src + rr * Dd + c);
      tile[rr][c] = a.x; tile[rr][c + 1] = a.y; tile[rr][c + 2] = a.z; tile[rr][c + 3] = a.w;
    }
  }
  __syncthreads();
  {
    const int d  = t >> 2;
    const int sc = (t & 3) << 4;
    unsigned short* dst = vt + ((long)bh * Dd + d) * Ss + s0 + sc;
    u16x8 v0, v1;
#pragma unroll
    for (int j = 0; j < 8; ++j) v0[j] = f2bf(tile[sc + j][d]);
#pragma unroll
    for (int j = 0; j < 8; ++j) v1[j] = f2bf(tile[sc + 8 + j][d]);
    *reinterpret_cast<u16x8*>(dst)     = v0;
    *reinterpret_cast<u16x8*>(dst + 8) = v1;
  }
}

// ---------------- main fused attention ----------------
// 1 block = 16 q-rows of one (b,h); 8 waves (512 thr); P (exp scores) in swizzled bf16 LDS.
// Phase 1: wave w owns keys [256w,256w+256). Phase 3: wave w owns key-half (w>>2),
// d-cols [16(w&3),+16); partials combined via LDS.
template<bool PRE>
__global__ __launch_bounds__(512, 4)
void attn_main(const float* __restrict__ qf, const float* __restrict__ kf,
               const float* __restrict__ vf, const int* __restrict__ mask,
               const unsigned short* __restrict__ qb,
               const unsigned short* __restrict__ kbp,
               const unsigned short* __restrict__ vt,
               const unsigned long long* __restrict__ bits,
               float* __restrict__ out, float* __restrict__ attn)
{
  __shared__ __align__(16) char Pb[16 * 2048 * 2];      // 64 KB
  __shared__ __align__(16) float Opart[2][16][64];      // 8 KB key-half partials
  __shared__ float rpart[8][16];
  __shared__ float rinv[16];

  const int tid  = threadIdx.x;
  const int wave = tid >> 6;
  const int lane = tid & 63;
  const int l15  = lane & 15;
  const int lg   = lane >> 4;

  const int bh    = blockIdx.x >> 7;
  const int qbase = (blockIdx.x & 127) << 4;

  // Q fragments (B operand of swapped QK^T): col q = lane&15, k-dim = d
  bf16x8 qfrag0, qfrag1;
  {
    const long qrow = (long)(bh * Ss + qbase + l15) * Dd + lg * 8;
    if (PRE) {
      qfrag0 = *reinterpret_cast<const bf16x8*>(qb + qrow);
      qfrag1 = *reinterpret_cast<const bf16x8*>(qb + qrow + 32);
    } else {
      qfrag0 = cvt8(qf + qrow);
      qfrag1 = cvt8(qf + qrow + 32);
    }
  }

  float psum = 0.f;
  const long mrow = (long)(bh * Ss + qbase + l15) * Ss;   // this lane's q-row (element index)

  // Phase 1: S^T = K·Q^T per 16-key tile; exp+mask; scatter into LDS; rowsum
  for (int it = 0; it < 16; ++it) {
    const int key0 = (wave << 8) + (it << 4);
    bf16x8 kfrag0, kfrag1;
    const long krow = (long)(bh * Ss + key0 + l15) * Dd + lg * 8;
    if (PRE) {
      kfrag0 = *reinterpret_cast<const bf16x8*>(kbp + krow);
      kfrag1 = *reinterpret_cast<const bf16x8*>(kbp + krow + 32);
    } else {
      kfrag0 = cvt8(kf + krow);
      kfrag1 = cvt8(kf + krow + 32);
    }
    const int k0 = key0 + (lg << 2);                      // 4 consecutive keys per lane
    unsigned mm;
    if (PRE) {
      const unsigned long long e = (unsigned long long)(mrow + k0);
      const unsigned long long w = bits[e >> 6];
      mm = (unsigned)(w >> ((int)e & 63)) & 0xFu;
    } else {
      const int4 m4 = *reinterpret_cast<const int4*>(mask + mrow + k0);
      mm = (m4.x ? 1u : 0u) | (m4.y ? 2u : 0u) | (m4.z ? 4u : 0u) | (m4.w ? 8u : 0u);
    }
    f32x4 acc = {0.f, 0.f, 0.f, 0.f};
    acc = __builtin_amdgcn_mfma_f32_16x16x32_bf16(kfrag0, qfrag0, acc, 0, 0, 0);
    acc = __builtin_amdgcn_mfma_f32_16x16x32_bf16(kfrag1, qfrag1, acc, 0, 0, 0);
    const float p0 = (mm & 1u) ? __expf(acc[0] * SCALE) : 0.f;
    const float p1 = (mm & 2u) ? __expf(acc[1] * SCALE) : 0.f;
    const float p2 = (mm & 4u) ? __expf(acc[2] * SCALE) : 0.f;
    const float p3 = (mm & 8u) ? __expf(acc[3] * SCALE) : 0.f;
    psum += (p0 + p1) + (p2 + p3);
    uint2 w2;
    w2.x = (unsigned)f2bf(p0) | ((unsigned)f2bf(p1) << 16);
    w2.y = (unsigned)f2bf(p2) | ((unsigned)f2bf(p3) << 16);
    *reinterpret_cast<uint2*>(Pb + pidx(l15, k0)) = w2;
  }

  // row-sum reduce: lanes with equal l15 share a q-row
  psum += __shfl_xor(psum, 16);
  psum += __shfl_xor(psum, 32);
  if (lane < 16) rpart[wave][l15] = psum;
  __syncthreads();
  if (tid < 16) {
    float t = 0.f;
#pragma unroll
    for (int w = 0; w < 8; ++w) t += rpart[w][tid];
    rinv[tid] = (t > 0.f) ? (1.f / t) : 0.f;
  }
  __syncthreads();

  // Phase 2: normalize + write attn (fp32, coalesced 16B, nontemporal)
  {
    const int r  = tid >> 5;                 // 16 rows over 512 threads
    const int cs = (tid & 31) << 3;
    const float inv = rinv[r];
    float* arow = attn + (long)(bh * Ss + qbase + r) * Ss;
#pragma unroll
    for (int it = 0; it < 8; ++it) {
      const int c0 = cs + (it << 8);
      const uint4 pk = *reinterpret_cast<const uint4*>(Pb + pidx(r, c0));
      f32x4 o0, o1;
      o0[0] = bflo(pk.x) * inv; o0[1] = bfhi(pk.x) * inv;
      o0[2] = bflo(pk.y) * inv; o0[3] = bfhi(pk.y) * inv;
      o1[0] = bflo(pk.z) * inv; o1[1] = bfhi(pk.z) * inv;
      o1[2] = bflo(pk.w) * inv; o1[3] = bfhi(pk.w) * inv;
      __builtin_nontemporal_store(o0, reinterpret_cast<f32x4*>(arow + c0));
      __builtin_nontemporal_store(o1, reinterpret_cast<f32x4*>(arow + c0 + 4));
    }
  }

  // Phase 3: O = P·V; wave w: key-half (w>>2), d-cols [16*(w&3),+16)
  {
    const int half = wave >> 2;
    const int dcol = ((wave & 3) << 4) + l15;
    f32x4 oacc = {0.f, 0.f, 0.f, 0.f};
    const unsigned short* vrow = PRE ? (vt + (long)(bh * Dd + dcol) * Ss) : nullptr;
    const float* vcolf = PRE ? nullptr : (vf + (long)bh * Ss * Dd + dcol);
    const int kbeg = half << 10;
    for (int kk = kbeg; kk < kbeg + 1024; kk += 32) {
      const int ka = kk + (lg << 3);
      const bf16x8 afrag = *reinterpret_cast<const bf16x8*>(Pb + pidx(l15, ka));
      bf16x8 bfrag;
      if (PRE) {
        bfrag = *reinterpret_cast<const bf16x8*>(vrow + ka);
      } else {
#pragma unroll
        for (int e = 0; e < 8; ++e) bfrag[e] = (short)f2bf(vcolf[(long)(ka + e) * Dd]);
      }
      oacc = __builtin_amdgcn_mfma_f32_16x16x32_bf16(afrag, bfrag, oacc, 0, 0, 0);
    }
#pragma unroll
    for (int rg = 0; rg < 4; ++rg)
      Opart[half][(lg << 2) + rg][dcol] = oacc[rg];
  }
  __syncthreads();
  // combine halves + scale + coalesced f32x4 out store
  if (tid < 256) {
    const int r = tid >> 4;
    const f32x4 a = *reinterpret_cast<const f32x4*>(&Opart[0][r][(tid & 15) << 2]);
    const f32x4 b = *reinterpret_cast<const f32x4*>(&Opart[1][r][(tid & 15) << 2]);
    f32x4 t = a + b;
    t *= rinv[r];
    *reinterpret_cast<f32x4*>(out + (long)(bh * Ss + qbase) * Dd + (tid << 2)) = t;
  }
}

extern "C" void kernel_launch(void* const* d_in, const int* in_sizes, int n_in,
                              void* d_out, int out_size, void* d_ws, size_t ws_size,
                              hipStream_t stream)
{
  const float* q    = (const float*)d_in[0];
  const float* k    = (const float*)d_in[1];
  const float* v    = (const float*)d_in[2];
  const int*   mask = (const int*)d_in[3];
  float* out  = (float*)d_out;
  float* attn = out + QKV_ELEMS;

  const size_t bf16_bytes = (size_t)QKV_ELEMS * 2 * 3;          // qb + kb + vt
  const size_t bits_bytes = (size_t)(MASK_ELEMS >> 3);          // 32 MiB
  const size_t need = bf16_bytes + bits_bytes;
  if (ws_size >= need) {
    unsigned short* qb = (unsigned short*)d_ws;
    unsigned short* kb = qb + QKV_ELEMS;
    unsigned short* vt = kb + QKV_ELEMS;
    unsigned long long* bits = (unsigned long long*)((char*)d_ws + bf16_bytes);
    hipLaunchKernelGGL(bitpack, dim3(2048), dim3(256), 0, stream, mask, bits);
    hipLaunchKernelGGL(cvt_qk, dim3((unsigned)(QKV_ELEMS / 1024)), dim3(256), 0, stream, q, k, qb, kb);
    hipLaunchKernelGGL(cvt_vt, dim3(BH * 32), dim3(256), 0, stream, v, vt);
    hipLaunchKernelGGL((attn_main<true>), dim3(BH * 128), dim3(512), 0, stream,
                       q, k, v, mask, qb, kb, vt, bits, out, attn);
  } else {
    hipLaunchKernelGGL((attn_main<false>), dim3(BH * 128), dim3(512), 0, stream,
                       q, k, v, mask, nullptr, nullptr, nullptr, nullptr, out, attn);
  }
}

// Round 9
// 863.980 us; speedup vs baseline: 1.5360x; 1.0593x over previous
//
#include <hip/hip_runtime.h>
#include <hip/hip_bf16.h>

typedef short bf16x8 __attribute__((ext_vector_type(8)));
typedef float f32x4 __attribute__((ext_vector_type(4)));
typedef int   i32x4 __attribute__((ext_vector_type(4)));
typedef unsigned short u16x8 __attribute__((ext_vector_type(8)));

#define DEVI static __device__ __forceinline__

constexpr int Bb = 4, Hh = 16, Ss = 2048, Dd = 64;
constexpr int BH = Bb * Hh;
constexpr float SCALE = 0.125f;                    // 1/sqrt(64)
constexpr long QKV_ELEMS = (long)BH * Ss * Dd;     // 8,388,608

DEVI unsigned short f2bf(float f) {
  __hip_bfloat16 h = __float2bfloat16(f);
  unsigned short u;
  __builtin_memcpy(&u, &h, 2);
  return u;
}
DEVI float bflo(unsigned int u) { unsigned int x = u << 16;        float f; __builtin_memcpy(&f, &x, 4); return f; }
DEVI float bfhi(unsigned int u) { unsigned int x = u & 0xffff0000u; float f; __builtin_memcpy(&f, &x, 4); return f; }

// swizzled byte offset into the P LDS tile: row q (16 rows x 4096B), XOR spreads banks
DEVI int pidx(int q, int k) { return (q << 12) + ((k << 1) ^ ((q & 7) << 4)); }

DEVI bf16x8 cvt8(const float* p) {
  float4 a = *reinterpret_cast<const float4*>(p);
  float4 b = *reinterpret_cast<const float4*>(p + 4);
  bf16x8 r;
  r[0] = (short)f2bf(a.x); r[1] = (short)f2bf(a.y); r[2] = (short)f2bf(a.z); r[3] = (short)f2bf(a.w);
  r[4] = (short)f2bf(b.x); r[5] = (short)f2bf(b.y); r[6] = (short)f2bf(b.z); r[7] = (short)f2bf(b.w);
  return r;
}

// ---------------- prologue: fp32 -> bf16 casts ----------------
__global__ __launch_bounds__(256) void cvt_qk(const float* __restrict__ q, const float* __restrict__ k,
                                              unsigned short* __restrict__ qb, unsigned short* __restrict__ kb)
{
  const long i = ((long)blockIdx.x * 256 + threadIdx.x) * 4;
  if (i >= QKV_ELEMS) return;
  const float4 a = *reinterpret_cast<const float4*>(q + i);
  ushort4 oa; oa.x = f2bf(a.x); oa.y = f2bf(a.y); oa.z = f2bf(a.z); oa.w = f2bf(a.w);
  *reinterpret_cast<ushort4*>(qb + i) = oa;
  const float4 b = *reinterpret_cast<const float4*>(k + i);
  ushort4 ob; ob.x = f2bf(b.x); ob.y = f2bf(b.y); ob.z = f2bf(b.z); ob.w = f2bf(b.w);
  *reinterpret_cast<ushort4*>(kb + i) = ob;
}

// V [bh][s][d] fp32 -> Vt [bh][d][s] bf16
__global__ __launch_bounds__(256) void cvt_vt(const float* __restrict__ v, unsigned short* __restrict__ vt)
{
  __shared__ float tile[64][65];
  const int bh = blockIdx.x >> 5;
  const int s0 = (blockIdx.x & 31) << 6;
  const int t  = threadIdx.x;
  {
    const int c = (t & 15) << 2;
    const float* src = v + ((long)bh * Ss + s0) * Dd;
    for (int rr = (t >> 4); rr < 64; rr += 16) {
      const float4 a = *reinterpret_cast<const float4*>(src + rr * Dd + c);
      tile[rr][c] = a.x; tile[rr][c + 1] = a.y; tile[rr][c + 2] = a.z; tile[rr][c + 3] = a.w;
    }
  }
  __syncthreads();
  {
    const int d  = t >> 2;
    const int sc = (t & 3) << 4;
    unsigned short* dst = vt + ((long)bh * Dd + d) * Ss + s0 + sc;
    u16x8 v0, v1;
#pragma unroll
    for (int j = 0; j < 8; ++j) v0[j] = f2bf(tile[sc + j][d]);
#pragma unroll
    for (int j = 0; j < 8; ++j) v1[j] = f2bf(tile[sc + 8 + j][d]);
    *reinterpret_cast<u16x8*>(dst)     = v0;
    *reinterpret_cast<u16x8*>(dst + 8) = v1;
  }
}

// ---------------- main fused attention ----------------
// 1 block = 16 q-rows of one (b,h); 8 waves (512 thr); P (exp scores) in swizzled bf16 LDS.
// Mask read directly (nt int4, 1-deep register prefetch). Plain stores throughout.
// Phase 1: wave w owns keys [256w,256w+256). Phase 3: wave w owns key-half (w>>2),
// d-cols [16(w&3),+16); partials combined via LDS.
template<bool PRE>
__global__ __launch_bounds__(512, 4)
void attn_main(const float* __restrict__ qf, const float* __restrict__ kf,
               const float* __restrict__ vf, const int* __restrict__ mask,
               const unsigned short* __restrict__ qb,
               const unsigned short* __restrict__ kbp,
               const unsigned short* __restrict__ vt,
               float* __restrict__ out, float* __restrict__ attn)
{
  __shared__ __align__(16) char Pb[16 * 2048 * 2];      // 64 KB
  __shared__ __align__(16) float Opart[2][16][64];      // 8 KB key-half partials
  __shared__ float rpart[8][16];
  __shared__ float rinv[16];

  const int tid  = threadIdx.x;
  const int wave = tid >> 6;
  const int lane = tid & 63;
  const int l15  = lane & 15;
  const int lg   = lane >> 4;

  const int bh    = blockIdx.x >> 7;
  const int qbase = (blockIdx.x & 127) << 4;

  // Q fragments (B operand of swapped QK^T): col q = lane&15, k-dim = d
  bf16x8 qfrag0, qfrag1;
  {
    const long qrow = (long)(bh * Ss + qbase + l15) * Dd + lg * 8;
    if (PRE) {
      qfrag0 = *reinterpret_cast<const bf16x8*>(qb + qrow);
      qfrag1 = *reinterpret_cast<const bf16x8*>(qb + qrow + 32);
    } else {
      qfrag0 = cvt8(qf + qrow);
      qfrag1 = cvt8(qf + qrow + 32);
    }
  }

  float psum = 0.f;
  const long mrow = (long)(bh * Ss + qbase + l15) * Ss;   // this lane's q-row (element index)
  const int keyw = wave << 8;                             // wave's 256-key range
  const int* mbase = mask + mrow + keyw + (lg << 2);      // this lane's 4-key mask slot

  // Phase 1: S^T = K·Q^T per 16-key tile; exp+mask; scatter into LDS; rowsum
  i32x4 mcur = __builtin_nontemporal_load(reinterpret_cast<const i32x4*>(mbase));
  for (int it = 0; it < 16; ++it) {
    i32x4 mnext;
    if (it < 15)
      mnext = __builtin_nontemporal_load(reinterpret_cast<const i32x4*>(mbase + ((it + 1) << 4)));
    const int key0 = keyw + (it << 4);
    bf16x8 kfrag0, kfrag1;
    const long krow = (long)(bh * Ss + key0 + l15) * Dd + lg * 8;
    if (PRE) {
      kfrag0 = *reinterpret_cast<const bf16x8*>(kbp + krow);
      kfrag1 = *reinterpret_cast<const bf16x8*>(kbp + krow + 32);
    } else {
      kfrag0 = cvt8(kf + krow);
      kfrag1 = cvt8(kf + krow + 32);
    }
    f32x4 acc = {0.f, 0.f, 0.f, 0.f};
    acc = __builtin_amdgcn_mfma_f32_16x16x32_bf16(kfrag0, qfrag0, acc, 0, 0, 0);
    acc = __builtin_amdgcn_mfma_f32_16x16x32_bf16(kfrag1, qfrag1, acc, 0, 0, 0);
    const float p0 = mcur[0] ? __expf(acc[0] * SCALE) : 0.f;
    const float p1 = mcur[1] ? __expf(acc[1] * SCALE) : 0.f;
    const float p2 = mcur[2] ? __expf(acc[2] * SCALE) : 0.f;
    const float p3 = mcur[3] ? __expf(acc[3] * SCALE) : 0.f;
    psum += (p0 + p1) + (p2 + p3);
    uint2 w2;
    w2.x = (unsigned)f2bf(p0) | ((unsigned)f2bf(p1) << 16);
    w2.y = (unsigned)f2bf(p2) | ((unsigned)f2bf(p3) << 16);
    *reinterpret_cast<uint2*>(Pb + pidx(l15, key0 + (lg << 2))) = w2;
    if (it < 15) mcur = mnext;
  }

  // row-sum reduce: lanes with equal l15 share a q-row
  psum += __shfl_xor(psum, 16);
  psum += __shfl_xor(psum, 32);
  if (lane < 16) rpart[wave][l15] = psum;
  __syncthreads();
  if (tid < 16) {
    float t = 0.f;
#pragma unroll
    for (int w = 0; w < 8; ++w) t += rpart[w][tid];
    rinv[tid] = (t > 0.f) ? (1.f / t) : 0.f;
  }
  __syncthreads();

  // Phase 2: normalize + write attn (fp32, coalesced 16B, plain stores — byte-exact)
  {
    const int r  = tid >> 5;                 // 16 rows over 512 threads
    const int cs = (tid & 31) << 3;
    const float inv = rinv[r];
    float* arow = attn + (long)(bh * Ss + qbase + r) * Ss;
#pragma unroll
    for (int it = 0; it < 8; ++it) {
      const int c0 = cs + (it << 8);
      const uint4 pk = *reinterpret_cast<const uint4*>(Pb + pidx(r, c0));
      f32x4 o0, o1;
      o0[0] = bflo(pk.x) * inv; o0[1] = bfhi(pk.x) * inv;
      o0[2] = bflo(pk.y) * inv; o0[3] = bfhi(pk.y) * inv;
      o1[0] = bflo(pk.z) * inv; o1[1] = bfhi(pk.z) * inv;
      o1[2] = bflo(pk.w) * inv; o1[3] = bfhi(pk.w) * inv;
      *reinterpret_cast<f32x4*>(arow + c0)     = o0;
      *reinterpret_cast<f32x4*>(arow + c0 + 4) = o1;
    }
  }

  // Phase 3: O = P·V; wave w: key-half (w>>2), d-cols [16*(w&3),+16)
  {
    const int half = wave >> 2;
    const int dcol = ((wave & 3) << 4) + l15;
    f32x4 oacc = {0.f, 0.f, 0.f, 0.f};
    const unsigned short* vrow = PRE ? (vt + (long)(bh * Dd + dcol) * Ss) : nullptr;
    const float* vcolf = PRE ? nullptr : (vf + (long)bh * Ss * Dd + dcol);
    const int kbeg = half << 10;
    for (int kk = kbeg; kk < kbeg + 1024; kk += 32) {
      const int ka = kk + (lg << 3);
      const bf16x8 afrag = *reinterpret_cast<const bf16x8*>(Pb + pidx(l15, ka));
      bf16x8 bfrag;
      if (PRE) {
        bfrag = *reinterpret_cast<const bf16x8*>(vrow + ka);
      } else {
#pragma unroll
        for (int e = 0; e < 8; ++e) bfrag[e] = (short)f2bf(vcolf[(long)(ka + e) * Dd]);
      }
      oacc = __builtin_amdgcn_mfma_f32_16x16x32_bf16(afrag, bfrag, oacc, 0, 0, 0);
    }
#pragma unroll
    for (int rg = 0; rg < 4; ++rg)
      Opart[half][(lg << 2) + rg][dcol] = oacc[rg];
  }
  __syncthreads();
  // combine halves + scale + coalesced f32x4 out store
  if (tid < 256) {
    const int r = tid >> 4;
    const f32x4 a = *reinterpret_cast<const f32x4*>(&Opart[0][r][(tid & 15) << 2]);
    const f32x4 b = *reinterpret_cast<const f32x4*>(&Opart[1][r][(tid & 15) << 2]);
    f32x4 t = a + b;
    t *= rinv[r];
    *reinterpret_cast<f32x4*>(out + (long)(bh * Ss + qbase) * Dd + (tid << 2)) = t;
  }
}

extern "C" void kernel_launch(void* const* d_in, const int* in_sizes, int n_in,
                              void* d_out, int out_size, void* d_ws, size_t ws_size,
                              hipStream_t stream)
{
  const float* q    = (const float*)d_in[0];
  const float* k    = (const float*)d_in[1];
  const float* v    = (const float*)d_in[2];
  const int*   mask = (const int*)d_in[3];
  float* out  = (float*)d_out;
  float* attn = out + QKV_ELEMS;

  const size_t bf16_bytes = (size_t)QKV_ELEMS * 2 * 3;          // qb + kb + vt
  if (ws_size >= bf16_bytes) {
    unsigned short* qb = (unsigned short*)d_ws;
    unsigned short* kb = qb + QKV_ELEMS;
    unsigned short* vt = kb + QKV_ELEMS;
    hipLaunchKernelGGL(cvt_qk, dim3((unsigned)(QKV_ELEMS / 1024)), dim3(256), 0, stream, q, k, qb, kb);
    hipLaunchKernelGGL(cvt_vt, dim3(BH * 32), dim3(256), 0, stream, v, vt);
    hipLaunchKernelGGL((attn_main<true>), dim3(BH * 128), dim3(512), 0, stream,
                       q, k, v, mask, qb, kb, vt, out, attn);
  } else {
    hipLaunchKernelGGL((attn_main<false>), dim3(BH * 128), dim3(512), 0, stream,
                       q, k, v, mask, nullptr, nullptr, nullptr, out, attn);
  }
}